// Round 3
// baseline (232.080 us; speedup 1.0000x reference)
//
#include <hip/hip_runtime.h>
#include <hip/hip_bf16.h>

#define BATCH 16
#define NV    20000
#define FIN   64
#define NCOUT 64
#define NK    16
#define TOTROWS  (BATCH * NV)      // 320000
#define NTILES   (TOTROWS / 16)    // 20000 row-tiles of 16
#define TPX      (NTILES / 8)      // 2500 tiles per XCD (2 batches)

typedef __attribute__((ext_vector_type(8))) short bf16x8;   // 8 bf16 (4 VGPRs)
typedef __attribute__((ext_vector_type(4))) float f32x4;    // MFMA acc
typedef __attribute__((ext_vector_type(4))) unsigned short u16x4;

__device__ __forceinline__ short f2b(float f) {
    __hip_bfloat16 h = __float2bfloat16(f);   // RTNE
    return __builtin_bit_cast(short, h);
}

// ---------------------------------------------------------------------------
// Pass A: one x-sweep, MFMA 16x16x32 bf16.
//   p[row][c] = x[row]@Wx[:,c] + bias[c]  -> out (fp32)
//   z[row][c] = x[row]@(Wn[:,c]/16)       -> ws  (bf16)
// ROUND-3: occupancy 3->4 blocks/CU. Explicit prefetch removed (was neutral:
// TLP covers it). MFMA split into two groups of 8 (accP -> out epilogue,
// accZ -> z epilogue) so accumulator lifetimes halve: peak VGPR ~116 fits
// the 128 cap of __launch_bounds__(256,4), and group-1 stores drain under
// group-2 MFMA. Blocks XCD-pinned like pass B (z produced+consumed on the
// same XCD's L2).
// Col-tile t covers global cols {4m+t}: out = 1 dwordx4/row, z = 1 dwordx2.
// ---------------------------------------------------------------------------
__global__ __launch_bounds__(256, 4) void convnet_gemm(
    const float* __restrict__ x,      // (320000, 64)
    const float* __restrict__ Wx,     // (64, 64)
    const float* __restrict__ Wn,     // (64, 64)
    const float* __restrict__ bias,   // (64)
    __hip_bfloat16* __restrict__ z,   // (320000, 64) bf16  [ws]
    float* __restrict__ out)          // (320000, 64) fp32  (gets p)
{
    const int lane = threadIdx.x & 63;
    const int m    = lane & 15;    // row-in-tile (A), selects col group (B)
    const int quad = lane >> 4;    // 0..3

    // B fragments: bf[t][h], t 0..3 = Wx (-> p), t 4..7 = Wn/16 (-> z).
    // frag[j] = W[k][colmap], k = 32*h + quad*8 + j, colmap = 4*m + (t&3).
    bf16x8 bf[8][2];
#pragma unroll
    for (int t = 0; t < 8; ++t) {
        const float* W = (t < 4) ? Wx : Wn;
        const float scale = (t < 4) ? 1.0f : (1.0f / 16.0f);
        const int c = 4 * m + (t & 3);
#pragma unroll
        for (int h = 0; h < 2; ++h) {
            bf16x8 fr;
#pragma unroll
            for (int j = 0; j < 8; ++j) {
                const int f = 32 * h + quad * 8 + j;
                fr[j] = f2b(W[f * NCOUT + c] * scale);
            }
            bf[t][h] = fr;
        }
    }
    float bias_q[4];
#pragma unroll
    for (int t = 0; t < 4; ++t) bias_q[t] = bias[4 * m + t];

    // XCD-pinned tile walk: xcd handles tiles [xcd*2500, (xcd+1)*2500).
    const int xcd = blockIdx.x & 7;
    const int bi  = blockIdx.x >> 3;                        // 0..127
    const int wl  = bi * 4 + ((int)threadIdx.x >> 6);       // 0..511
    const int WPX = (gridDim.x >> 3) * 4;                   // 512 waves/xcd

    for (int t0 = wl; t0 < TPX; t0 += WPX) {
        const int rt = __builtin_amdgcn_readfirstlane(xcd * TPX + t0);
        const float* xt =
            x + (size_t)rt * (16 * FIN) + (size_t)m * FIN + quad * 8;

        const float4 La0 = ((const float4*)xt)[0];
        const float4 La1 = ((const float4*)xt)[1];
        const float4 Lb0 = ((const float4*)(xt + 32))[0];
        const float4 Lb1 = ((const float4*)(xt + 32))[1];

        bf16x8 af0, af1;
        af0[0] = f2b(La0.x); af0[1] = f2b(La0.y); af0[2] = f2b(La0.z); af0[3] = f2b(La0.w);
        af0[4] = f2b(La1.x); af0[5] = f2b(La1.y); af0[6] = f2b(La1.z); af0[7] = f2b(La1.w);
        af1[0] = f2b(Lb0.x); af1[1] = f2b(Lb0.y); af1[2] = f2b(Lb0.z); af1[3] = f2b(Lb0.w);
        af1[4] = f2b(Lb1.x); af1[5] = f2b(Lb1.y); af1[6] = f2b(Lb1.z); af1[7] = f2b(Lb1.w);

        const size_t rbase = (size_t)rt * 16 + quad * 4;

        // Group 1: p tiles (t 0..3)
        {
            f32x4 accP[4];
#pragma unroll
            for (int t = 0; t < 4; ++t) accP[t] = (f32x4){0.f, 0.f, 0.f, 0.f};
#pragma unroll
            for (int t = 0; t < 4; ++t)
                accP[t] = __builtin_amdgcn_mfma_f32_16x16x32_bf16(af0, bf[t][0], accP[t], 0, 0, 0);
#pragma unroll
            for (int t = 0; t < 4; ++t)
                accP[t] = __builtin_amdgcn_mfma_f32_16x16x32_bf16(af1, bf[t][1], accP[t], 0, 0, 0);
#pragma unroll
            for (int r = 0; r < 4; ++r) {
                const size_t orow = (rbase + r) * NCOUT + 4 * m;
                float4 o;
                o.x = accP[0][r] + bias_q[0];
                o.y = accP[1][r] + bias_q[1];
                o.z = accP[2][r] + bias_q[2];
                o.w = accP[3][r] + bias_q[3];
                *(float4*)(out + orow) = o;
            }
        }
        // Group 2: z tiles (t 4..7) — MFMA overlaps group-1 store drain.
        {
            f32x4 accZ[4];
#pragma unroll
            for (int t = 0; t < 4; ++t) accZ[t] = (f32x4){0.f, 0.f, 0.f, 0.f};
#pragma unroll
            for (int t = 0; t < 4; ++t)
                accZ[t] = __builtin_amdgcn_mfma_f32_16x16x32_bf16(af0, bf[t + 4][0], accZ[t], 0, 0, 0);
#pragma unroll
            for (int t = 0; t < 4; ++t)
                accZ[t] = __builtin_amdgcn_mfma_f32_16x16x32_bf16(af1, bf[t + 4][1], accZ[t], 0, 0, 0);
#pragma unroll
            for (int r = 0; r < 4; ++r) {
                const size_t orow = (rbase + r) * NCOUT + 4 * m;
                u16x4 zz;
                zz.x = (unsigned short)f2b(accZ[0][r]);
                zz.y = (unsigned short)f2b(accZ[1][r]);
                zz.z = (unsigned short)f2b(accZ[2][r]);
                zz.w = (unsigned short)f2b(accZ[3][r]);
                *(u16x4*)(z + orow) = zz;
            }
        }
    }
}

// ---------------------------------------------------------------------------
// Pass B: out[b,v,:] += sum_k z[b, nbr[v,k]-1, :]  (idx==0 = zero pad).
// Wave = 4 consecutive rows; lane = (s = lane>>4 sub-row, c = lane&15 col-grp)
// -> dwordx2 gathers (8B/lane). Wave-scalar bases via readfirstlane(g).
// ROUND-3: latency attack. (a) grid 1536->2048 + __launch_bounds__(256,8):
// 8 blocks/CU = 32 waves/CU (was 47% occupancy). (b) neighbor ids loaded as
// 4x int4 (was 16x dword). (c) out float4 RMW-read issued at the TOP of the
// iteration so its ~900cy HBM miss hides under the 16 gathers.
// ---------------------------------------------------------------------------
__global__ __launch_bounds__(256, 8) void convnet_gather(
    const int* __restrict__ nbr,           // (20000, 16), values in [0, V]
    const __hip_bfloat16* __restrict__ z,  // (320000, 64) bf16
    float* __restrict__ out)               // (320000, 64) fp32, has p already
{
    const int lane = threadIdx.x & 63;
    const int s    = lane >> 4;            // sub-row 0..3
    const int c    = lane & 15;            // col group (4 cols)
    const int xcd  = blockIdx.x & 7;
    const int bi   = blockIdx.x >> 3;                        // 0..255
    const int wl   = bi * 4 + ((int)threadIdx.x >> 6);       // 0..1023
    const int WPX  = (gridDim.x >> 3) * 4;                   // 1024 waves/xcd

    const int zcol   = c * 8;              // byte col offset (4 bf16)
    const int GROUPS = (2 * NV) / 4;       // 10000 groups per xcd

    for (int g = wl; g < GROUPS; g += WPX) {
        const int gu = __builtin_amdgcn_readfirstlane(g);
        const int bl = (gu >= NV / 4) ? 1 : 0;
        const int b  = 2 * xcd + bl;
        const int v0 = gu * 4 - bl * NV;
        const int row0 = b * NV + v0;      // global out row of sub-row 0

        // out RMW read issued early: hides HBM miss under the gathers below.
        float4* o = (float4*)(out + (size_t)(row0 + s) * NCOUT + 4 * c);
        float4 ov = *o;

        // neighbor ids for this lane's sub-row: 4x int4 (one 64B line/row).
        const int4* nb4 =
            (const int4*)((const char*)nbr + (size_t)(v0 + s) * (NK * 4));
        const int4 i0 = nb4[0];
        const int4 i1 = nb4[1];
        const int4 i2 = nb4[2];
        const int4 i3 = nb4[3];
        int id[NK];
        id[0] = i0.x; id[1] = i0.y; id[2]  = i0.z; id[3]  = i0.w;
        id[4] = i1.x; id[5] = i1.y; id[6]  = i1.z; id[7]  = i1.w;
        id[8] = i2.x; id[9] = i2.y; id[10] = i2.z; id[11] = i2.w;
        id[12] = i3.x; id[13] = i3.y; id[14] = i3.z; id[15] = i3.w;

        const char* zb = (const char*)z + (size_t)b * NV * 128;  // batch base
        float a0 = 0.f, a1 = 0.f, a2 = 0.f, a3 = 0.f;
#pragma unroll
        for (int k = 0; k < NK; ++k) {
            const int idx = id[k];
            int sel = idx - 1;
            sel = sel < 0 ? 0 : sel;       // clamp pad (row 0 read, masked)
            const uint2 d = *(const uint2*)(zb + (size_t)(unsigned)(sel * 128 + zcol));
            const unsigned dx = idx ? d.x : 0u;
            const unsigned dy = idx ? d.y : 0u;
            a0 += __builtin_bit_cast(float, dx << 16);
            a1 += __builtin_bit_cast(float, dx & 0xFFFF0000u);
            a2 += __builtin_bit_cast(float, dy << 16);
            a3 += __builtin_bit_cast(float, dy & 0xFFFF0000u);
        }

        ov.x += a0; ov.y += a1; ov.z += a2; ov.w += a3;
        *o = ov;
    }
}

extern "C" void kernel_launch(void* const* d_in, const int* in_sizes, int n_in,
                              void* d_out, int out_size, void* d_ws, size_t ws_size,
                              hipStream_t stream) {
    const float* x    = (const float*)d_in[0];
    const float* Wx   = (const float*)d_in[1];
    const float* Wn   = (const float*)d_in[2];
    const float* bias = (const float*)d_in[3];
    const int*   nbr  = (const int*)d_in[4];
    float* out = (float*)d_out;

    __hip_bfloat16* z = (__hip_bfloat16*)d_ws;   // 40.96 MB (proven fits ws)

    hipLaunchKernelGGL(convnet_gemm, dim3(1024), dim3(256), 0, stream,
                       x, Wx, Wn, bias, z, out);
    hipLaunchKernelGGL(convnet_gather, dim3(2048), dim3(256), 0, stream,
                       nbr, z, out);
}